// Round 3
// baseline (2655.341 us; speedup 1.0000x reference)
//
#include <hip/hip_runtime.h>
#include <hip/hip_bf16.h>

typedef __bf16 bf16x8 __attribute__((ext_vector_type(8)));
typedef float f32x4 __attribute__((ext_vector_type(4)));
typedef float f32x8 __attribute__((ext_vector_type(8)));

#define B_ 8
#define L_ 1024
#define D_ 1024
#define H_ 16
#define DPH_ 64
#define MAXREL_ 32
#define NREL_ 65
#define BQ_ 16

__device__ __forceinline__ f32x4 mfma16x16x32(bf16x8 a, bf16x8 b, f32x4 c) {
    return __builtin_amdgcn_mfma_f32_16x16x32_bf16(a, b, c, 0, 0, 0);
}

__device__ __forceinline__ bf16x8 cvt8(const float* p) {
    f32x8 v = *(const f32x8*)p;
    bf16x8 r;
    #pragma unroll
    for (int i = 0; i < 8; ++i) r[i] = (__bf16)v[i];
    return r;
}

// out_bf16 = (X @ W^T + bias) * scale ; X: MxK f32, W: NxK f32 (row-major).
// MFMA 16x16x32: A lane reads X[row0+(l&15)][k0+8*(l>>4)+i],
// B lane reads W[col0+(l&15)][k0+8*(l>>4)+i]. C/D: col=l&15, row=(l>>4)*4+i.
// MODE 0: out[m*N+n]. MODE 1 (V transpose): out[(m>>10)<<20 | n*1024 | (m&1023)].
template <int MODE>
__global__ __launch_bounds__(256) void gemm_ff(
    const float* __restrict__ X, const float* __restrict__ W,
    const float* __restrict__ bias, __bf16* __restrict__ out,
    int N, int K, float scale)
{
    const int lane = threadIdx.x & 63;
    const int w    = threadIdx.x >> 6;
    const int row0 = blockIdx.x * 32 + (w >> 1) * 16;
    const int col0 = blockIdx.y * 32 + (w & 1) * 16;
    const int lr = lane & 15;
    const int lk = lane >> 4;

    const float* ap = X + (size_t)(row0 + lr) * K + 8 * lk;
    const float* bp = W + (size_t)(col0 + lr) * K + 8 * lk;

    f32x4 acc = {0.f, 0.f, 0.f, 0.f};
    for (int k0 = 0; k0 < K; k0 += 32) {
        acc = mfma16x16x32(cvt8(ap + k0), cvt8(bp + k0), acc);
    }
    const int n = col0 + lr;
    const float bv = bias[n];
    #pragma unroll
    for (int i = 0; i < 4; ++i) {
        const int m = row0 + lk * 4 + i;
        const float v = (acc[i] + bv) * scale;
        if (MODE == 0) {
            out[(size_t)m * N + n] = (__bf16)v;
        } else {
            out[((size_t)(m >> 10) << 20) + (size_t)n * L_ + (m & 1023)] = (__bf16)v;
        }
    }
}

// out_f32 = A @ W^T + bias ; A: MxK bf16, W: NxK f32.
__global__ __launch_bounds__(256) void gemm_bf_f32out(
    const __bf16* __restrict__ A, const float* __restrict__ W,
    const float* __restrict__ bias, float* __restrict__ out,
    int N, int K)
{
    const int lane = threadIdx.x & 63;
    const int w    = threadIdx.x >> 6;
    const int row0 = blockIdx.x * 32 + (w >> 1) * 16;
    const int col0 = blockIdx.y * 32 + (w & 1) * 16;
    const int lr = lane & 15;
    const int lk = lane >> 4;

    const __bf16* ap = A + (size_t)(row0 + lr) * K + 8 * lk;
    const float*  bp = W + (size_t)(col0 + lr) * K + 8 * lk;

    f32x4 acc = {0.f, 0.f, 0.f, 0.f};
    for (int k0 = 0; k0 < K; k0 += 32) {
        bf16x8 a = *(const bf16x8*)(ap + k0);
        acc = mfma16x16x32(a, cvt8(bp + k0), acc);
    }
    const int n = col0 + lr;
    const float bv = bias[n];
    #pragma unroll
    for (int i = 0; i < 4; ++i) {
        const int m = row0 + lk * 4 + i;
        out[(size_t)m * N + n] = acc[i] + bv;
    }
}

// One block = (b, h, 16 query rows). 256 threads = 4 waves.
// Q,K: [B*L][D] bf16 (Q pre-scaled by 1/8). Vt: [b][h*64+d][pos] bf16.
__global__ __launch_bounds__(256) void attn_kernel(
    const __bf16* __restrict__ Q, const __bf16* __restrict__ K,
    const __bf16* __restrict__ Vt, const int* __restrict__ mask,
    const float* __restrict__ relg, __bf16* __restrict__ ctx,
    float* __restrict__ attn0)
{
    __shared__ float s_sc[BQ_][1028];      // scores/attn, padded
    __shared__ float s_rq[BQ_][NREL_];     // q . rel_emb[j]
    __shared__ float s_arel[BQ_][NREL_];   // bucketed attn sums
    __shared__ float s_rel[NREL_][DPH_];   // rel_emb f32
    __shared__ float s_q[BQ_][DPH_];
    __shared__ float s_red[BQ_][16];
    __shared__ float s_rmax[BQ_];
    __shared__ float s_rsum[BQ_];

    const int tid = threadIdx.x;
    const int bid = blockIdx.x;
    const int qb = bid & 63;
    const int h  = (bid >> 6) & 15;
    const int b  = bid >> 10;
    const int q0 = qb * BQ_;
    const int lane = tid & 63;
    const int w = tid >> 6;
    const int lr = lane & 15;
    const int lk = lane >> 4;

    const size_t bhbase = ((size_t)b * L_) * D_ + (size_t)h * DPH_;

    // ---- P0: stage q rows (f32), rel_emb (f32), zero arel ----
    for (int idx = tid; idx < BQ_ * DPH_; idx += 256) {
        int r = idx >> 6, d = idx & 63;
        s_q[r][d] = (float)Q[bhbase + (size_t)(q0 + r) * D_ + d];
    }
    for (int idx = tid; idx < NREL_ * DPH_; idx += 256)
        s_rel[idx >> 6][idx & 63] = relg[idx];
    for (int idx = tid; idx < BQ_ * NREL_; idx += 256)
        s_arel[idx / NREL_][idx % NREL_] = 0.f;
    __syncthreads();

    // rq[q][j] = sum_d q[d] * rel_emb[j][d]
    for (int idx = tid; idx < BQ_ * NREL_; idx += 256) {
        int r = idx / NREL_, j = idx % NREL_;
        float s = 0.f;
        #pragma unroll 8
        for (int d = 0; d < DPH_; ++d) s += s_q[r][d] * s_rel[j][d];
        s_rq[r][j] = s;
    }
    __syncthreads();

    // ---- P1: scores = Q K^T + rel bias, masked ----
    const __bf16* aptr = Q + bhbase + (size_t)(q0 + lr) * D_ + 8 * lk;
    const bf16x8 a0 = *(const bf16x8*)(aptr);
    const bf16x8 a1 = *(const bf16x8*)(aptr + 32);
    for (int ct = w * 16; ct < w * 16 + 16; ++ct) {
        const int kt0 = ct * 16;
        const __bf16* bptr = K + bhbase + (size_t)(kt0 + lr) * D_ + 8 * lk;
        f32x4 acc = {0.f, 0.f, 0.f, 0.f};
        acc = mfma16x16x32(a0, *(const bf16x8*)(bptr), acc);
        acc = mfma16x16x32(a1, *(const bf16x8*)(bptr + 32), acc);
        const int kg = kt0 + lr;                    // C/D col = lane&15
        const bool msk = mask[b * L_ + kg] != 0;
        #pragma unroll
        for (int i = 0; i < 4; ++i) {
            const int r = lk * 4 + i;               // C/D row
            int dr = kg - (q0 + r);
            dr = dr < -MAXREL_ ? -MAXREL_ : (dr > MAXREL_ ? MAXREL_ : dr);
            float v = acc[i] + s_rq[r][dr + MAXREL_];
            if (msk) v = -1e18f;
            s_sc[r][kg] = v;
        }
    }
    __syncthreads();

    // ---- P2: softmax (row = tid&15, sub = tid>>4) ----
    {
        const int r = tid & 15, sub = tid >> 4;
        const int qgl = q0 + r;
        float m = -3.4e38f;
        for (int j = 0; j < 64; ++j) m = fmaxf(m, s_sc[r][sub + 16 * j]);
        s_red[r][sub] = m;
        __syncthreads();
        if (tid < 16) {
            float mm = s_red[tid][0];
            for (int s = 1; s < 16; ++s) mm = fmaxf(mm, s_red[tid][s]);
            s_rmax[tid] = mm;
        }
        __syncthreads();
        const float rm = s_rmax[r];
        float psum = 0.f;
        for (int j = 0; j < 64; ++j) {
            const int c = sub + 16 * j;
            const float e = __expf(s_sc[r][c] - rm);
            s_sc[r][c] = e;
            psum += e;
        }
        s_red[r][sub] = psum;
        __syncthreads();
        if (tid < 16) {
            float ss = 0.f;
            for (int s = 0; s < 16; ++s) ss += s_red[tid][s];
            s_rsum[tid] = ss;
        }
        __syncthreads();
        const float inv = 1.0f / s_rsum[r];
        float acc0 = 0.f, acc64 = 0.f;
        for (int j = 0; j < 64; ++j) {
            const int c = sub + 16 * j;
            const float aP = s_sc[r][c] * inv;
            s_sc[r][c] = aP;
            const int dd = c - qgl;
            if (dd < -MAXREL_)      acc0 += aP;
            else if (dd > MAXREL_)  acc64 += aP;
            else atomicAdd(&s_arel[r][dd + MAXREL_], aP);
            if (h == 0) attn0[((size_t)b * L_ + qgl) * L_ + c] = aP;
        }
        if (acc0 != 0.f)  atomicAdd(&s_arel[r][0], acc0);
        if (acc64 != 0.f) atomicAdd(&s_arel[r][NREL_ - 1], acc64);
    }
    __syncthreads();

    // ---- P3: ctx = attn @ V + arel @ rel_emb ; wave w owns d-tile w ----
    {
        f32x4 acc = {0.f, 0.f, 0.f, 0.f};
        const __bf16* vbase = Vt + ((size_t)b << 20)
                            + (size_t)(h * DPH_ + w * 16 + lr) * L_ + 8 * lk;
        for (int ks = 0; ks < 32; ++ks) {
            const float* prow = &s_sc[lr][ks * 32 + 8 * lk];
            bf16x8 af;
            #pragma unroll
            for (int i = 0; i < 8; ++i) af[i] = (__bf16)prow[i];
            const bf16x8 bfv = *(const bf16x8*)(vbase + ks * 32);
            acc = mfma16x16x32(af, bfv, acc);
        }
        #pragma unroll
        for (int i = 0; i < 4; ++i) {
            const int r = lk * 4 + i;
            const int dd = w * 16 + lr;
            float v = acc[i];
            for (int j = 0; j < NREL_; ++j) v += s_arel[r][j] * s_rel[j][dd];
            ctx[((size_t)b * L_ + q0 + r) * D_ + h * DPH_ + dd] = (__bf16)v;
        }
    }
}

extern "C" void kernel_launch(void* const* d_in, const int* in_sizes, int n_in,
                              void* d_out, int out_size, void* d_ws, size_t ws_size,
                              hipStream_t stream) {
    const float* key   = (const float*)d_in[0];
    const float* value = (const float*)d_in[1];
    const float* query = (const float*)d_in[2];
    const int*   mask  = (const int*)d_in[3];
    const float* Wq = (const float*)d_in[4];
    const float* bq = (const float*)d_in[5];
    const float* Wk = (const float*)d_in[6];
    const float* bk = (const float*)d_in[7];
    const float* Wv = (const float*)d_in[8];
    const float* bv = (const float*)d_in[9];
    const float* Wo = (const float*)d_in[10];
    const float* bo = (const float*)d_in[11];
    const float* relg = (const float*)d_in[12];

    float* out   = (float*)d_out;
    float* attn0 = out + (size_t)B_ * L_ * D_;   // top_attn region (f32)

    char* ws = (char*)d_ws;
    __bf16* Qw   = (__bf16*)(ws);
    __bf16* Kw   = (__bf16*)(ws + ((size_t)16 << 20));
    __bf16* Vtw  = (__bf16*)(ws + ((size_t)32 << 20));
    __bf16* Ctxw = (__bf16*)(ws + ((size_t)48 << 20));

    const dim3 blk(256);
    const dim3 gP(B_ * L_ / 32, D_ / 32);   // 256 x 32

    // Projections (Q pre-scaled by 1/sqrt(DPH)=0.125)
    gemm_ff<0><<<gP, blk, 0, stream>>>(query, Wq, bq, Qw, D_, D_, 0.125f);
    gemm_ff<0><<<gP, blk, 0, stream>>>(key,   Wk, bk, Kw, D_, D_, 1.0f);
    gemm_ff<1><<<gP, blk, 0, stream>>>(value, Wv, bv, Vtw, D_, D_, 1.0f);

    // Attention: grid = B*H*(L/BQ) = 8*16*64
    attn_kernel<<<B_ * H_ * (L_ / BQ_), blk, 0, stream>>>(
        Qw, Kw, Vtw, mask, relg, Ctxw, attn0);

    // Output projection -> f32 out
    gemm_bf_f32out<<<gP, blk, 0, stream>>>(Ctxw, Wo, bo, out, D_, D_);
}

// Round 4
// 436.591 us; speedup vs baseline: 6.0820x; 6.0820x over previous
//
#include <hip/hip_runtime.h>
#include <hip/hip_bf16.h>

typedef __bf16 bf16x8 __attribute__((ext_vector_type(8)));
typedef __bf16 bf16x4 __attribute__((ext_vector_type(4)));
typedef float f32x4 __attribute__((ext_vector_type(4)));
typedef float f32x8 __attribute__((ext_vector_type(8)));

#define B_ 8
#define L_ 1024
#define D_ 1024
#define H_ 16
#define DPH_ 64
#define MAXREL_ 32
#define NREL_ 65

__device__ __forceinline__ f32x4 mfma16x16x32(bf16x8 a, bf16x8 b, f32x4 c) {
    return __builtin_amdgcn_mfma_f32_16x16x32_bf16(a, b, c, 0, 0, 0);
}

__device__ __forceinline__ bf16x8 ld_any(const float* p) {
    f32x8 v = *(const f32x8*)p;
    bf16x8 r;
    #pragma unroll
    for (int i = 0; i < 8; ++i) r[i] = (__bf16)v[i];
    return r;
}
__device__ __forceinline__ bf16x8 ld_any(const __bf16* p) { return *(const bf16x8*)p; }

// ---------------------------------------------------------------------------
// 128x128-tile GEMM: out = (X @ W^T + bias) * scale. X: MxK (f32 or bf16),
// W: NxK f32. 4 waves, each 64x64 (4x4 frags of 16x16x32). LDS tiles
// [128][64] bf16 with 16B-chunk XOR swizzle (chunk ^= row&7) -> conflict-free
// ds_read_b128 / ds_write_b128. Register prefetch of tile kt+1 overlaps MFMA.
// MODE 0: bf16 out[m*N+n]; MODE 1: bf16 Vt[(m>>10)<<20 | n*1024 | m&1023]
// (packed 4-row bf16x4 stores); MODE 2: f32 out[m*N+n].
// ---------------------------------------------------------------------------
template <int MODE, typename TA>
__global__ __launch_bounds__(256) void gemm128(
    const TA* __restrict__ X, const float* __restrict__ Wt,
    const float* __restrict__ bias, void* __restrict__ outp,
    int M, int N, int K, float scale)
{
    __shared__ __bf16 sA[128 * 64];
    __shared__ __bf16 sB[128 * 64];

    const int tid = threadIdx.x;
    const int nbn = N >> 7;
    const int nwg = (M >> 7) * nbn;
    const int wg  = ((int)blockIdx.x & 7) * (nwg >> 3) + ((int)blockIdx.x >> 3);
    const int row0 = (wg / nbn) * 128, col0 = (wg % nbn) * 128;
    const int lane = tid & 63, w = tid >> 6, lr = lane & 15, lk = lane >> 4;
    const int wm = w >> 1, wn = w & 1;
    const int srow = tid >> 3;     // staging row 0..31
    const int schk = tid & 7;      // staging 16B chunk

    bf16x8 ra[4], rb[4];
    f32x4 acc[4][4];
    #pragma unroll
    for (int a = 0; a < 4; ++a)
        #pragma unroll
        for (int b = 0; b < 4; ++b) acc[a][b] = (f32x4){0.f, 0.f, 0.f, 0.f};

    const int nkt = K >> 6;
    {   // preload kt=0
        const int kc = schk * 8;
        #pragma unroll
        for (int u = 0; u < 4; ++u) {
            const int r = u * 32 + srow;
            ra[u] = ld_any(X  + (size_t)(row0 + r) * K + kc);
            rb[u] = ld_any(Wt + (size_t)(col0 + r) * K + kc);
        }
    }
    for (int kt = 0; kt < nkt; ++kt) {
        __syncthreads();
        #pragma unroll
        for (int u = 0; u < 4; ++u) {
            const int r = u * 32 + srow;
            *(bf16x8*)&sA[r * 64 + ((schk ^ (r & 7)) * 8)] = ra[u];
            *(bf16x8*)&sB[r * 64 + ((schk ^ (r & 7)) * 8)] = rb[u];
        }
        __syncthreads();
        if (kt + 1 < nkt) {
            const int kc = (kt + 1) * 64 + schk * 8;
            #pragma unroll
            for (int u = 0; u < 4; ++u) {
                const int r = u * 32 + srow;
                ra[u] = ld_any(X  + (size_t)(row0 + r) * K + kc);
                rb[u] = ld_any(Wt + (size_t)(col0 + r) * K + kc);
            }
        }
        #pragma unroll
        for (int kk = 0; kk < 2; ++kk) {
            bf16x8 af[4], bf[4];
            #pragma unroll
            for (int mi = 0; mi < 4; ++mi) {
                const int r = wm * 64 + mi * 16 + lr;
                af[mi] = *(const bf16x8*)&sA[r * 64 + (((kk * 4 + lk) ^ (r & 7)) * 8)];
            }
            #pragma unroll
            for (int ni = 0; ni < 4; ++ni) {
                const int r = wn * 64 + ni * 16 + lr;
                bf[ni] = *(const bf16x8*)&sB[r * 64 + (((kk * 4 + lk) ^ (r & 7)) * 8)];
            }
            #pragma unroll
            for (int mi = 0; mi < 4; ++mi)
                #pragma unroll
                for (int ni = 0; ni < 4; ++ni)
                    acc[mi][ni] = mfma16x16x32(af[mi], bf[ni], acc[mi][ni]);
        }
    }

    #pragma unroll
    for (int ni = 0; ni < 4; ++ni) {
        const int n = col0 + wn * 64 + ni * 16 + lr;
        const float bv = bias[n];
        #pragma unroll
        for (int mi = 0; mi < 4; ++mi) {
            const int m0 = row0 + wm * 64 + mi * 16 + lk * 4;
            if (MODE == 0) {
                #pragma unroll
                for (int i = 0; i < 4; ++i)
                    ((__bf16*)outp)[(size_t)(m0 + i) * N + n] =
                        (__bf16)((acc[mi][ni][i] + bv) * scale);
            } else if (MODE == 1) {
                bf16x4 v4;
                #pragma unroll
                for (int i = 0; i < 4; ++i) v4[i] = (__bf16)(acc[mi][ni][i] + bv);
                *(bf16x4*)((__bf16*)outp + ((size_t)(m0 >> 10) << 20)
                           + (size_t)n * L_ + (m0 & 1023)) = v4;
            } else {
                #pragma unroll
                for (int i = 0; i < 4; ++i)
                    ((float*)outp)[(size_t)(m0 + i) * N + n] = acc[mi][ni][i] + bv;
            }
        }
    }
}

// ---------------------------------------------------------------------------
// Attention v2: block = (b,h,16 q-rows), 4 waves, wave w owns keys
// [w*256,(w+1)*256). Swapped QK^T (A=K rows, B=Q rows) => lane holds 64
// scores of q-row (lane&15) in registers: in-lane softmax + 2 shfl_xor +
// cross-wave LDS. P -> LDS bf16 [16][1032] (pad kills the 16-way conflict);
// each lane packs 4 consecutive k's (b64 write). PV: wave w owns d-tile w.
// rel bias via rq[q][j] table built with 5 MFMAs; mask as 1024-bit LDS set.
// ---------------------------------------------------------------------------
__global__ __launch_bounds__(256) void attn_v2(
    const __bf16* __restrict__ Q, const __bf16* __restrict__ K,
    const __bf16* __restrict__ Vt, const int* __restrict__ mask,
    const float* __restrict__ relg, __bf16* __restrict__ ctx,
    float* __restrict__ attn0)
{
    __shared__ __bf16 sP[16][1032];
    __shared__ float s_rq[16][66];
    __shared__ float s_arel[16][66];
    __shared__ __bf16 s_relb[NREL_][DPH_];
    __shared__ float s_rmax[4][16];
    __shared__ float s_rsum[4][16];
    __shared__ unsigned s_mbits[32];
    __shared__ float s_inv[16];

    const int tid = threadIdx.x;
    const int wg = ((int)blockIdx.x & 7) * 1024 + ((int)blockIdx.x >> 3);
    const int qb = wg & 63, h = (wg >> 6) & 15, b = wg >> 10;
    const int q0 = qb * 16;
    const int lane = tid & 63, w = tid >> 6, lr = lane & 15, lk = lane >> 4;
    const size_t bh = (size_t)b * (L_ * D_) + (size_t)h * DPH_;

    // Q fragments (B-operand): lane lr -> q-row q0+lr
    const __bf16* qp = Q + bh + (size_t)(q0 + lr) * D_ + 8 * lk;
    const bf16x8 qf0 = *(const bf16x8*)qp;
    const bf16x8 qf1 = *(const bf16x8*)(qp + 32);

    // mask bitset (1024 bits)
    #pragma unroll
    for (int rr = 0; rr < 4; ++rr) {
        const int k = rr * 256 + w * 64 + lane;
        const unsigned long long bal = __ballot(mask[b * L_ + k] != 0);
        if (lane == 0) {
            s_mbits[rr * 8 + w * 2]     = (unsigned)bal;
            s_mbits[rr * 8 + w * 2 + 1] = (unsigned)(bal >> 32);
        }
    }
    // rel -> LDS bf16; zero arel
    for (int i = tid; i < NREL_ * DPH_; i += 256)
        ((__bf16*)s_relb)[i] = (__bf16)relg[i];
    for (int i = tid; i < 16 * 66; i += 256) ((float*)s_arel)[i] = 0.f;

    // rq[q][j] = q . rel_emb[j] via MFMA (A=rel rows, B=Q rows)
    for (int jt = w; jt < 5; jt += (w == 0 ? 4 : 8)) {
        const int jr = jt * 16 + lr;
        const int jc = jr > 64 ? 64 : jr;
        const float* rp = relg + jc * 64 + 8 * lk;
        f32x4 rq = {0.f, 0.f, 0.f, 0.f};
        rq = mfma16x16x32(ld_any(rp), qf0, rq);
        rq = mfma16x16x32(ld_any(rp + 32), qf1, rq);
        #pragma unroll
        for (int i = 0; i < 4; ++i) {
            const int jj = jt * 16 + lk * 4 + i;
            if (jj <= 64) s_rq[lr][jj] = rq[i];
        }
    }
    __syncthreads();

    // QK^T into registers: p[kt][i] = scores[key = kbase+kt*16+lk*4+i][q0+lr]
    float p[16][4];
    const int kbase = w * 256;
    #pragma unroll
    for (int kt = 0; kt < 16; ++kt) {
        const int k0 = kbase + kt * 16;
        const __bf16* kp = K + bh + (size_t)(k0 + lr) * D_ + 8 * lk;
        f32x4 acc = {0.f, 0.f, 0.f, 0.f};
        acc = mfma16x16x32(*(const bf16x8*)kp, qf0, acc);
        acc = mfma16x16x32(*(const bf16x8*)(kp + 32), qf1, acc);
        const int kb = k0 + lk * 4;
        const unsigned mword = s_mbits[kb >> 5];
        #pragma unroll
        for (int i = 0; i < 4; ++i) {
            const int k = kb + i;
            const int dd = k - (q0 + lr);
            const int j = dd < -MAXREL_ ? 0 : (dd > MAXREL_ ? 64 : dd + MAXREL_);
            float v = acc[i] + s_rq[lr][j];
            if ((mword >> (k & 31)) & 1u) v = -1e18f;
            p[kt][i] = v;
        }
    }

    // softmax: in-lane + xor(16,32) + cross-wave
    float mx = p[0][0];
    #pragma unroll
    for (int kt = 0; kt < 16; ++kt)
        #pragma unroll
        for (int i = 0; i < 4; ++i) mx = fmaxf(mx, p[kt][i]);
    mx = fmaxf(mx, __shfl_xor(mx, 16, 64));
    mx = fmaxf(mx, __shfl_xor(mx, 32, 64));
    if (lane < 16) s_rmax[w][lr] = mx;
    __syncthreads();
    const float rm = fmaxf(fmaxf(s_rmax[0][lr], s_rmax[1][lr]),
                           fmaxf(s_rmax[2][lr], s_rmax[3][lr]));
    float sum = 0.f;
    #pragma unroll
    for (int kt = 0; kt < 16; ++kt)
        #pragma unroll
        for (int i = 0; i < 4; ++i) {
            const float e = __expf(p[kt][i] - rm);
            p[kt][i] = e;
            sum += e;
        }
    sum += __shfl_xor(sum, 16, 64);
    sum += __shfl_xor(sum, 32, 64);
    if (lane < 16) s_rsum[w][lr] = sum;
    __syncthreads();
    const float tot = s_rsum[0][lr] + s_rsum[1][lr] + s_rsum[2][lr] + s_rsum[3][lr];
    const float inv = 1.f / tot;
    if (w == 0 && lane < 16) s_inv[lr] = inv;

    // arel buckets (unnormalized; unique writer for interior), attn0, P->LDS
    float c0 = 0.f, c64 = 0.f;
    float* a0p = attn0 + ((size_t)b * L_ + q0 + lr) * L_;
    #pragma unroll
    for (int kt = 0; kt < 16; ++kt) {
        const int kb = kbase + kt * 16 + lk * 4;
        bf16x4 v4;
        #pragma unroll
        for (int i = 0; i < 4; ++i) v4[i] = (__bf16)p[kt][i];
        *(bf16x4*)&sP[lr][kb] = v4;
        #pragma unroll
        for (int i = 0; i < 4; ++i) {
            const int k = kb + i;
            const int dd = k - (q0 + lr);
            const float pv = p[kt][i];
            if (h == 0) a0p[k] = pv * inv;
            if (dd <= -MAXREL_)      c0  += pv;
            else if (dd >= MAXREL_)  c64 += pv;
            else                     s_arel[lr][dd + MAXREL_] = pv;
        }
    }
    if (c0  != 0.f) atomicAdd(&s_arel[lr][0],  c0);
    if (c64 != 0.f) atomicAdd(&s_arel[lr][64], c64);
    __syncthreads();

    // PV: wave w owns d-tile w. A = P rows (lane lr -> q-row), B = Vt rows.
    f32x4 acc = {0.f, 0.f, 0.f, 0.f};
    const __bf16* vp = Vt + ((size_t)b << 20)
                     + (size_t)(h * DPH_ + w * 16 + lr) * L_ + 8 * lk;
    #pragma unroll
    for (int ks = 0; ks < 32; ++ks) {
        const bf16x8 af = *(const bf16x8*)&sP[lr][ks * 32 + 8 * lk];
        const bf16x8 bv = *(const bf16x8*)(vp + ks * 32);
        acc = mfma16x16x32(af, bv, acc);
    }
    const int d = w * 16 + lr;
    float t[4] = {0.f, 0.f, 0.f, 0.f};
    for (int j = 0; j < NREL_; ++j) {
        const float rv = (float)s_relb[j][d];
        #pragma unroll
        for (int i = 0; i < 4; ++i) t[i] += s_arel[lk * 4 + i][j] * rv;
    }
    #pragma unroll
    for (int i = 0; i < 4; ++i) {
        const int r = lk * 4 + i;
        const float outv = (acc[i] + t[i]) * s_inv[r];
        ctx[((size_t)b * L_ + q0 + r) * D_ + h * DPH_ + d] = (__bf16)outv;
    }
}

extern "C" void kernel_launch(void* const* d_in, const int* in_sizes, int n_in,
                              void* d_out, int out_size, void* d_ws, size_t ws_size,
                              hipStream_t stream) {
    const float* key   = (const float*)d_in[0];
    const float* value = (const float*)d_in[1];
    const float* query = (const float*)d_in[2];
    const int*   mask  = (const int*)d_in[3];
    const float* Wq = (const float*)d_in[4];
    const float* bq = (const float*)d_in[5];
    const float* Wk = (const float*)d_in[6];
    const float* bk = (const float*)d_in[7];
    const float* Wv = (const float*)d_in[8];
    const float* bv = (const float*)d_in[9];
    const float* Wo = (const float*)d_in[10];
    const float* bo = (const float*)d_in[11];
    const float* relg = (const float*)d_in[12];

    float* out   = (float*)d_out;
    float* attn0 = out + (size_t)B_ * L_ * D_;

    char* ws = (char*)d_ws;
    __bf16* Qw   = (__bf16*)(ws);
    __bf16* Kw   = (__bf16*)(ws + ((size_t)16 << 20));
    __bf16* Vtw  = (__bf16*)(ws + ((size_t)32 << 20));
    __bf16* Ctxw = (__bf16*)(ws + ((size_t)48 << 20));

    const dim3 blk(256);
    const int M = B_ * L_;
    const int ngemm = (M / 128) * (D_ / 128);   // 512

    gemm128<0, float><<<ngemm, blk, 0, stream>>>(query, Wq, bq, Qw, M, D_, D_, 0.125f);
    gemm128<0, float><<<ngemm, blk, 0, stream>>>(key,   Wk, bk, Kw, M, D_, D_, 1.0f);
    gemm128<1, float><<<ngemm, blk, 0, stream>>>(value, Wv, bv, Vtw, M, D_, D_, 1.0f);

    attn_v2<<<B_ * H_ * (L_ / 16), blk, 0, stream>>>(Qw, Kw, Vtw, mask, relg, Ctxw, attn0);

    gemm128<2, __bf16><<<ngemm, blk, 0, stream>>>(Ctxw, Wo, bo, out, M, D_, D_, 1.0f);
}

// Round 5
// 435.587 us; speedup vs baseline: 6.0960x; 1.0023x over previous
//
#include <hip/hip_runtime.h>
#include <hip/hip_bf16.h>

typedef __bf16 bf16x8 __attribute__((ext_vector_type(8)));
typedef __bf16 bf16x4 __attribute__((ext_vector_type(4)));
typedef float f32x4 __attribute__((ext_vector_type(4)));
typedef float f32x8 __attribute__((ext_vector_type(8)));

#define B_ 8
#define L_ 1024
#define D_ 1024
#define H_ 16
#define DPH_ 64
#define MAXREL_ 32
#define NREL_ 65

__device__ __forceinline__ f32x4 mfma16x16x32(bf16x8 a, bf16x8 b, f32x4 c) {
    return __builtin_amdgcn_mfma_f32_16x16x32_bf16(a, b, c, 0, 0, 0);
}

__device__ __forceinline__ bf16x8 ld_any(const float* p) {
    f32x8 v = *(const f32x8*)p;
    bf16x8 r;
    #pragma unroll
    for (int i = 0; i < 8; ++i) r[i] = (__bf16)v[i];
    return r;
}
__device__ __forceinline__ bf16x8 ld_any(const __bf16* p) { return *(const bf16x8*)p; }

// ---------------------------------------------------------------------------
// 128x128-tile GEMM: out = (X @ W^T + bias) * scale. X: MxK (f32 or bf16),
// W: NxK f32. 4 waves, each 64x64 (4x4 frags of 16x16x32). LDS tiles
// [128][64] bf16 with 16B-chunk XOR swizzle (chunk ^= row&7) -> conflict-free
// ds_read_b128 / ds_write_b128. Register prefetch of tile kt+1 overlaps MFMA.
// MODE 0: bf16 out[m*N+n]; MODE 1: bf16 Vt[(m>>10)<<20 | n*1024 | m&1023]
// (packed 4-row bf16x4 stores); MODE 2: f32 out[m*N+n].
// ---------------------------------------------------------------------------
template <int MODE, typename TA>
__global__ __launch_bounds__(256) void gemm128(
    const TA* __restrict__ X, const float* __restrict__ Wt,
    const float* __restrict__ bias, void* __restrict__ outp,
    int M, int N, int K, float scale)
{
    __shared__ __bf16 sA[128 * 64];
    __shared__ __bf16 sB[128 * 64];

    const int tid = threadIdx.x;
    const int nbn = N >> 7;
    const int nwg = (M >> 7) * nbn;
    const int wg  = ((int)blockIdx.x & 7) * (nwg >> 3) + ((int)blockIdx.x >> 3);
    const int row0 = (wg / nbn) * 128, col0 = (wg % nbn) * 128;
    const int lane = tid & 63, w = tid >> 6, lr = lane & 15, lk = lane >> 4;
    const int wm = w >> 1, wn = w & 1;
    const int srow = tid >> 3;     // staging row 0..31
    const int schk = tid & 7;      // staging 16B chunk

    bf16x8 ra[4], rb[4];
    f32x4 acc[4][4];
    #pragma unroll
    for (int a = 0; a < 4; ++a)
        #pragma unroll
        for (int b = 0; b < 4; ++b) acc[a][b] = (f32x4){0.f, 0.f, 0.f, 0.f};

    const int nkt = K >> 6;
    {   // preload kt=0
        const int kc = schk * 8;
        #pragma unroll
        for (int u = 0; u < 4; ++u) {
            const int r = u * 32 + srow;
            ra[u] = ld_any(X  + (size_t)(row0 + r) * K + kc);
            rb[u] = ld_any(Wt + (size_t)(col0 + r) * K + kc);
        }
    }
    for (int kt = 0; kt < nkt; ++kt) {
        __syncthreads();
        #pragma unroll
        for (int u = 0; u < 4; ++u) {
            const int r = u * 32 + srow;
            *(bf16x8*)&sA[r * 64 + ((schk ^ (r & 7)) * 8)] = ra[u];
            *(bf16x8*)&sB[r * 64 + ((schk ^ (r & 7)) * 8)] = rb[u];
        }
        __syncthreads();
        if (kt + 1 < nkt) {
            const int kc = (kt + 1) * 64 + schk * 8;
            #pragma unroll
            for (int u = 0; u < 4; ++u) {
                const int r = u * 32 + srow;
                ra[u] = ld_any(X  + (size_t)(row0 + r) * K + kc);
                rb[u] = ld_any(Wt + (size_t)(col0 + r) * K + kc);
            }
        }
        #pragma unroll
        for (int kk = 0; kk < 2; ++kk) {
            bf16x8 af[4], bf[4];
            #pragma unroll
            for (int mi = 0; mi < 4; ++mi) {
                const int r = wm * 64 + mi * 16 + lr;
                af[mi] = *(const bf16x8*)&sA[r * 64 + (((kk * 4 + lk) ^ (r & 7)) * 8)];
            }
            #pragma unroll
            for (int ni = 0; ni < 4; ++ni) {
                const int r = wn * 64 + ni * 16 + lr;
                bf[ni] = *(const bf16x8*)&sB[r * 64 + (((kk * 4 + lk) ^ (r & 7)) * 8)];
            }
            #pragma unroll
            for (int mi = 0; mi < 4; ++mi)
                #pragma unroll
                for (int ni = 0; ni < 4; ++ni)
                    acc[mi][ni] = mfma16x16x32(af[mi], bf[ni], acc[mi][ni]);
        }
    }

    #pragma unroll
    for (int ni = 0; ni < 4; ++ni) {
        const int n = col0 + wn * 64 + ni * 16 + lr;
        const float bv = bias[n];
        #pragma unroll
        for (int mi = 0; mi < 4; ++mi) {
            const int m0 = row0 + wm * 64 + mi * 16 + lk * 4;
            if (MODE == 0) {
                #pragma unroll
                for (int i = 0; i < 4; ++i)
                    ((__bf16*)outp)[(size_t)(m0 + i) * N + n] =
                        (__bf16)((acc[mi][ni][i] + bv) * scale);
            } else if (MODE == 1) {
                bf16x4 v4;
                #pragma unroll
                for (int i = 0; i < 4; ++i) v4[i] = (__bf16)(acc[mi][ni][i] + bv);
                *(bf16x4*)((__bf16*)outp + ((size_t)(m0 >> 10) << 20)
                           + (size_t)n * L_ + (m0 & 1023)) = v4;
            } else {
                #pragma unroll
                for (int i = 0; i < 4; ++i)
                    ((float*)outp)[(size_t)(m0 + i) * N + n] = acc[mi][ni][i] + bv;
            }
        }
    }
}

// ---------------------------------------------------------------------------
// Attention v2: block = (b,h,16 q-rows), 4 waves, wave w owns keys
// [w*256,(w+1)*256). Swapped QK^T (A=K rows, B=Q rows) => lane holds 64
// scores of q-row (lane&15) in registers: in-lane softmax + 2 shfl_xor +
// cross-wave LDS. P -> LDS bf16 [16][1032] (pad kills the 16-way conflict);
// each lane packs 4 consecutive k's (b64 write). PV: wave w owns d-tile w.
// rel bias via rq[q][j] table built with 5 MFMAs; mask as 1024-bit LDS set.
// ---------------------------------------------------------------------------
__global__ __launch_bounds__(256) void attn_v2(
    const __bf16* __restrict__ Q, const __bf16* __restrict__ K,
    const __bf16* __restrict__ Vt, const int* __restrict__ mask,
    const float* __restrict__ relg, __bf16* __restrict__ ctx,
    float* __restrict__ attn0)
{
    __shared__ __bf16 sP[16][1032];
    __shared__ float s_rq[16][66];
    __shared__ float s_arel[16][66];
    __shared__ __bf16 s_relb[NREL_][DPH_];
    __shared__ float s_rmax[4][16];
    __shared__ float s_rsum[4][16];
    __shared__ unsigned s_mbits[32];
    __shared__ float s_inv[16];

    const int tid = threadIdx.x;
    const int wg = ((int)blockIdx.x & 7) * 1024 + ((int)blockIdx.x >> 3);
    const int qb = wg & 63, h = (wg >> 6) & 15, b = wg >> 10;
    const int q0 = qb * 16;
    const int lane = tid & 63, w = tid >> 6, lr = lane & 15, lk = lane >> 4;
    const size_t bh = (size_t)b * (L_ * D_) + (size_t)h * DPH_;

    // Q fragments (B-operand): lane lr -> q-row q0+lr
    const __bf16* qp = Q + bh + (size_t)(q0 + lr) * D_ + 8 * lk;
    const bf16x8 qf0 = *(const bf16x8*)qp;
    const bf16x8 qf1 = *(const bf16x8*)(qp + 32);

    // mask bitset (1024 bits)
    #pragma unroll
    for (int rr = 0; rr < 4; ++rr) {
        const int k = rr * 256 + w * 64 + lane;
        const unsigned long long bal = __ballot(mask[b * L_ + k] != 0);
        if (lane == 0) {
            s_mbits[rr * 8 + w * 2]     = (unsigned)bal;
            s_mbits[rr * 8 + w * 2 + 1] = (unsigned)(bal >> 32);
        }
    }
    // rel -> LDS bf16; zero arel
    for (int i = tid; i < NREL_ * DPH_; i += 256)
        ((__bf16*)s_relb)[i] = (__bf16)relg[i];
    for (int i = tid; i < 16 * 66; i += 256) ((float*)s_arel)[i] = 0.f;

    // rq[q][j] = q . rel_emb[j] via MFMA (A=rel rows, B=Q rows)
    for (int jt = w; jt < 5; jt += (w == 0 ? 4 : 8)) {
        const int jr = jt * 16 + lr;
        const int jc = jr > 64 ? 64 : jr;
        const float* rp = relg + jc * 64 + 8 * lk;
        f32x4 rq = {0.f, 0.f, 0.f, 0.f};
        rq = mfma16x16x32(ld_any(rp), qf0, rq);
        rq = mfma16x16x32(ld_any(rp + 32), qf1, rq);
        #pragma unroll
        for (int i = 0; i < 4; ++i) {
            const int jj = jt * 16 + lk * 4 + i;
            if (jj <= 64) s_rq[lr][jj] = rq[i];
        }
    }
    __syncthreads();

    // QK^T into registers: p[kt][i] = scores[key = kbase+kt*16+lk*4+i][q0+lr]
    float p[16][4];
    const int kbase = w * 256;
    #pragma unroll
    for (int kt = 0; kt < 16; ++kt) {
        const int k0 = kbase + kt * 16;
        const __bf16* kp = K + bh + (size_t)(k0 + lr) * D_ + 8 * lk;
        f32x4 acc = {0.f, 0.f, 0.f, 0.f};
        acc = mfma16x16x32(*(const bf16x8*)kp, qf0, acc);
        acc = mfma16x16x32(*(const bf16x8*)(kp + 32), qf1, acc);
        const int kb = k0 + lk * 4;
        const unsigned mword = s_mbits[kb >> 5];
        #pragma unroll
        for (int i = 0; i < 4; ++i) {
            const int k = kb + i;
            const int dd = k - (q0 + lr);
            const int j = dd < -MAXREL_ ? 0 : (dd > MAXREL_ ? 64 : dd + MAXREL_);
            float v = acc[i] + s_rq[lr][j];
            if ((mword >> (k & 31)) & 1u) v = -1e18f;
            p[kt][i] = v;
        }
    }

    // softmax: in-lane + xor(16,32) + cross-wave
    float mx = p[0][0];
    #pragma unroll
    for (int kt = 0; kt < 16; ++kt)
        #pragma unroll
        for (int i = 0; i < 4; ++i) mx = fmaxf(mx, p[kt][i]);
    mx = fmaxf(mx, __shfl_xor(mx, 16, 64));
    mx = fmaxf(mx, __shfl_xor(mx, 32, 64));
    if (lane < 16) s_rmax[w][lr] = mx;
    __syncthreads();
    const float rm = fmaxf(fmaxf(s_rmax[0][lr], s_rmax[1][lr]),
                           fmaxf(s_rmax[2][lr], s_rmax[3][lr]));
    float sum = 0.f;
    #pragma unroll
    for (int kt = 0; kt < 16; ++kt)
        #pragma unroll
        for (int i = 0; i < 4; ++i) {
            const float e = __expf(p[kt][i] - rm);
            p[kt][i] = e;
            sum += e;
        }
    sum += __shfl_xor(sum, 16, 64);
    sum += __shfl_xor(sum, 32, 64);
    if (lane < 16) s_rsum[w][lr] = sum;
    __syncthreads();
    const float tot = s_rsum[0][lr] + s_rsum[1][lr] + s_rsum[2][lr] + s_rsum[3][lr];
    const float inv = 1.f / tot;
    if (w == 0 && lane < 16) s_inv[lr] = inv;

    // arel buckets (unnormalized; unique writer for interior), attn0, P->LDS
    float c0 = 0.f, c64 = 0.f;
    float* a0p = attn0 + ((size_t)b * L_ + q0 + lr) * L_;
    #pragma unroll
    for (int kt = 0; kt < 16; ++kt) {
        const int kb = kbase + kt * 16 + lk * 4;
        bf16x4 v4;
        #pragma unroll
        for (int i = 0; i < 4; ++i) v4[i] = (__bf16)p[kt][i];
        *(bf16x4*)&sP[lr][kb] = v4;
        #pragma unroll
        for (int i = 0; i < 4; ++i) {
            const int k = kb + i;
            const int dd = k - (q0 + lr);
            const float pv = p[kt][i];
            if (h == 0) a0p[k] = pv * inv;
            if (dd <= -MAXREL_)      c0  += pv;
            else if (dd >= MAXREL_)  c64 += pv;
            else                     s_arel[lr][dd + MAXREL_] = pv;
        }
    }
    if (c0  != 0.f) atomicAdd(&s_arel[lr][0],  c0);
    if (c64 != 0.f) atomicAdd(&s_arel[lr][64], c64);
    __syncthreads();

    // PV: wave w owns d-tile w. A = P rows (lane lr -> q-row), B = Vt rows.
    f32x4 acc = {0.f, 0.f, 0.f, 0.f};
    const __bf16* vp = Vt + ((size_t)b << 20)
                     + (size_t)(h * DPH_ + w * 16 + lr) * L_ + 8 * lk;
    #pragma unroll
    for (int ks = 0; ks < 32; ++ks) {
        const bf16x8 af = *(const bf16x8*)&sP[lr][ks * 32 + 8 * lk];
        const bf16x8 bv = *(const bf16x8*)(vp + ks * 32);
        acc = mfma16x16x32(af, bv, acc);
    }
    const int d = w * 16 + lr;
    float t[4] = {0.f, 0.f, 0.f, 0.f};
    for (int j = 0; j < NREL_; ++j) {
        const float rv = (float)s_relb[j][d];
        #pragma unroll
        for (int i = 0; i < 4; ++i) t[i] += s_arel[lk * 4 + i][j] * rv;
    }
    #pragma unroll
    for (int i = 0; i < 4; ++i) {
        const int r = lk * 4 + i;
        const float outv = (acc[i] + t[i]) * s_inv[r];
        ctx[((size_t)b * L_ + q0 + r) * D_ + h * DPH_ + d] = (__bf16)outv;
    }
}

extern "C" void kernel_launch(void* const* d_in, const int* in_sizes, int n_in,
                              void* d_out, int out_size, void* d_ws, size_t ws_size,
                              hipStream_t stream) {
    const float* key   = (const float*)d_in[0];
    const float* value = (const float*)d_in[1];
    const float* query = (const float*)d_in[2];
    const int*   mask  = (const int*)d_in[3];
    const float* Wq = (const float*)d_in[4];
    const float* bq = (const float*)d_in[5];
    const float* Wk = (const float*)d_in[6];
    const float* bk = (const float*)d_in[7];
    const float* Wv = (const float*)d_in[8];
    const float* bv = (const float*)d_in[9];
    const float* Wo = (const float*)d_in[10];
    const float* bo = (const float*)d_in[11];
    const float* relg = (const float*)d_in[12];

    float* out   = (float*)d_out;
    float* attn0 = out + (size_t)B_ * L_ * D_;

    char* ws = (char*)d_ws;
    __bf16* Qw   = (__bf16*)(ws);
    __bf16* Kw   = (__bf16*)(ws + ((size_t)16 << 20));
    __bf16* Vtw  = (__bf16*)(ws + ((size_t)32 << 20));
    __bf16* Ctxw = (__bf16*)(ws + ((size_t)48 << 20));

    const dim3 blk(256);
    const int M = B_ * L_;
    const int ngemm = (M / 128) * (D_ / 128);   // 512

    gemm128<0, float><<<ngemm, blk, 0, stream>>>(query, Wq, bq, Qw, M, D_, D_, 0.125f);
    gemm128<0, float><<<ngemm, blk, 0, stream>>>(key,   Wk, bk, Kw, M, D_, D_, 1.0f);
    gemm128<1, float><<<ngemm, blk, 0, stream>>>(value, Wv, bv, Vtw, M, D_, D_, 1.0f);

    attn_v2<<<B_ * H_ * (L_ / 16), blk, 0, stream>>>(Qw, Kw, Vtw, mask, relg, Ctxw, attn0);

    gemm128<2, __bf16><<<ngemm, blk, 0, stream>>>(Ctxw, Wo, bo, out, M, D_, D_, 1.0f);
}